// Round 8
// baseline (237.098 us; speedup 1.0000x reference)
//
#include <hip/hip_runtime.h>

// CausalSelfAttention: B=2, T=2048, C=1024, H=16, D=64
// bf16 MFMA. gemm_qkv: A-operand direct global->register frags (prefetched),
// B via LDS (XOR swizzle). S^T-form flash attn, fixed-C softmax, 2-way split-K.
// Standalone combine (R7's fused combine recomputed per n-block: regression).
// NOTE: __launch_bounds__(256,4) spills the acc tile (R6). Keep plain (256).
#define BSZ 2
#define SEQ 2048
#define NEMBD 1024
#define NHEAD 16
#define HDIM 64
#define BT (BSZ * SEQ)          // 4096
#define QKV_LD (3 * NEMBD)      // 3072
#define SCALE_LOG2E 0.1803368665f   // (1/sqrt(64)) * log2(e)

typedef unsigned short u16;
typedef __attribute__((ext_vector_type(8))) short short8;     // 8 bf16 (MFMA A/B frag)
typedef __attribute__((ext_vector_type(4))) float floatx4;    // MFMA C/D frag
typedef __attribute__((ext_vector_type(4))) unsigned short ushort4v;

#define MFMA16(a, b, c) __builtin_amdgcn_mfma_f32_16x16x32_bf16(a, b, c, 0, 0, 0)

__device__ __forceinline__ void gload_lds16(const void* g, void* l) {
  __builtin_amdgcn_global_load_lds(
      (const __attribute__((address_space(1))) unsigned int*)(g),
      (__attribute__((address_space(3))) unsigned int*)(l), 16, 0, 0);
}

__device__ __forceinline__ u16 f2bf(float f) {  // fp32 -> bf16 RNE
  unsigned int u = __builtin_bit_cast(unsigned int, f);
  u += 0x7FFFu + ((u >> 16) & 1u);
  return (u16)(u >> 16);
}

__device__ __forceinline__ float bf2f(u16 v) {
  return __builtin_bit_cast(float, (unsigned)v << 16);
}

// ---------------------------------------------------------------------------
// Fused fp32->bf16 conversion of x, w_attn, w_proj in one launch.
// ---------------------------------------------------------------------------
#define N_X  (BT * NEMBD)          // 4194304
#define N_WA (QKV_LD * NEMBD)      // 3145728
#define N_WP (NEMBD * NEMBD)       // 1048576
__global__ __launch_bounds__(256) void cvt_all(const float* __restrict__ x,
                                               const float* __restrict__ wa,
                                               const float* __restrict__ wp,
                                               u16* __restrict__ xb,
                                               u16* __restrict__ wab,
                                               u16* __restrict__ wpb) {
  int i = (blockIdx.x * 256 + threadIdx.x) * 8;
  const float* src;
  u16* dst;
  if (i < N_X)            { src = x + i;              dst = xb + i; }
  else if (i < N_X + N_WA){ src = wa + (i - N_X);     dst = wab + (i - N_X); }
  else                    { src = wp + (i - N_X - N_WA); dst = wpb + (i - N_X - N_WA); }
  float4 a = *(const float4*)(src);
  float4 b = *(const float4*)(src + 4);
  short8 o;
  o[0] = (short)f2bf(a.x); o[1] = (short)f2bf(a.y);
  o[2] = (short)f2bf(a.z); o[3] = (short)f2bf(a.w);
  o[4] = (short)f2bf(b.x); o[5] = (short)f2bf(b.y);
  o[6] = (short)f2bf(b.z); o[7] = (short)f2bf(b.w);
  *(short8*)(dst) = o;
}

// ---------------------------------------------------------------------------
// GEMM1: qkv = x @ w_attn^T. 128x128 tile, BK=64.
// A: direct global->register frags (16B/lane), prefetched one K-slab ahead —
//    no LDS, no barrier coupling; latency hides behind the MFMA phase.
// B: LDS via global_load_lds, XOR swizzle (row*64 + ((c>>3)^(row&7))*8+(c&7)).
// n0 < 2048 (Q,K): operand-SWAPPED MFMA -> lane packs 4 consecutive n.
// n0 >= 2048 (V): normal order -> lane packs 4 consecutive tokens -> vtg.
// ---------------------------------------------------------------------------
__global__ __launch_bounds__(256) void gemm_qkv(const u16* __restrict__ A,
                                                const u16* __restrict__ B,
                                                u16* __restrict__ qkb,
                                                u16* __restrict__ vtg) {
  __shared__ __align__(16) u16 Bs[128 * 64];  // 16 KB
  const int t = threadIdx.x;
  const int lane = t & 63, w = t >> 6;
  const int l15 = lane & 15, quad = lane >> 4;
  const int wm = w >> 1, wn = w & 1;
  const int m0 = blockIdx.y * 128, n0 = blockIdx.x * 128;
  const int is_v = (n0 >= 2 * NEMBD);

  // this lane's A-frag base: row (m0 + wm*64 + mt*16 + l15), col quad*8
  const u16* a0 = A + (size_t)(m0 + wm * 64 + l15) * NEMBD + quad * 8;

  floatx4 acc[4][4] = {};
  short8 afc[2][4], afn[2][4];

  // prologue: A frags for k0 = 0
#pragma unroll
  for (int kh = 0; kh < 2; ++kh)
#pragma unroll
    for (int mt = 0; mt < 4; ++mt)
      afc[kh][mt] = *(const short8*)(a0 + (size_t)mt * 16 * NEMBD + kh * 32);

  for (int k0 = 0; k0 < NEMBD; k0 += 64) {
    __syncthreads();
#pragma unroll
    for (int is = 0; is < 4; ++is) {
      int s = is * 256 + t;
      int row = s >> 3, pos = s & 7;
      int kc = pos ^ (row & 7);
      gload_lds16(B + (size_t)(n0 + row) * NEMBD + k0 + kc * 8, &Bs[s * 8]);
    }
    __syncthreads();
    // prefetch next K-slab's A frags (consumed next iteration)
    if (k0 + 64 < NEMBD) {
#pragma unroll
      for (int kh = 0; kh < 2; ++kh)
#pragma unroll
        for (int mt = 0; mt < 4; ++mt)
          afn[kh][mt] = *(const short8*)(a0 + (size_t)mt * 16 * NEMBD + k0 + 64 + kh * 32);
    }
#pragma unroll
    for (int kh = 0; kh < 2; ++kh) {
      short8 bfr[4];
#pragma unroll
      for (int nt = 0; nt < 4; ++nt) {
        int row = wn * 64 + nt * 16 + l15;
        bfr[nt] = *(const short8*)&Bs[row * 64 + (((kh * 4 + quad) ^ (row & 7)) * 8)];
      }
      if (is_v) {
#pragma unroll
        for (int mt = 0; mt < 4; ++mt)
#pragma unroll
          for (int nt = 0; nt < 4; ++nt)
            acc[mt][nt] = MFMA16(afc[kh][mt], bfr[nt], acc[mt][nt]);   // D[m][n]
      } else {
#pragma unroll
        for (int mt = 0; mt < 4; ++mt)
#pragma unroll
          for (int nt = 0; nt < 4; ++nt)
            acc[mt][nt] = MFMA16(bfr[nt], afc[kh][mt], acc[mt][nt]);   // D[n][m]
      }
    }
#pragma unroll
    for (int kh = 0; kh < 2; ++kh)
#pragma unroll
      for (int mt = 0; mt < 4; ++mt)
        afc[kh][mt] = afn[kh][mt];
  }

  if (is_v) {
    // D rows = tokens (quad*4+r), cols = hd (l15): pack 4 tokens -> vtg[hd][token]
#pragma unroll
    for (int mt = 0; mt < 4; ++mt)
#pragma unroll
      for (int nt = 0; nt < 4; ++nt) {
        int hd = n0 + wn * 64 + nt * 16 + l15 - 2 * NEMBD;
        int token = m0 + wm * 64 + mt * 16 + quad * 4;
        int b = token >> 11, tp = token & (SEQ - 1);
        ushort4v pk;
#pragma unroll
        for (int r = 0; r < 4; ++r) pk[r] = f2bf(acc[mt][nt][r]);
        *(ushort4v*)&vtg[((size_t)(b * NEMBD + hd)) * SEQ + tp] = pk;
      }
  } else {
    // swapped: D rows = n (quad*4+r), cols = token (l15): pack 4 n -> qkb[token][n]
#pragma unroll
    for (int mt = 0; mt < 4; ++mt) {
      size_t token = (size_t)(m0 + wm * 64 + mt * 16 + l15);
#pragma unroll
      for (int nt = 0; nt < 4; ++nt) {
        int nc = n0 + wn * 64 + nt * 16 + quad * 4;
        ushort4v pk;
#pragma unroll
        for (int r = 0; r < 4; ++r) pk[r] = f2bf(acc[mt][nt][r]);
        *(ushort4v*)&qkb[token * 2048 + nc] = pk;
      }
    }
  }
}

// ---------------------------------------------------------------------------
// Flash attention (causal), S^T form, fixed-C softmax (C=8), 2-way split-K.
// ---------------------------------------------------------------------------
__global__ __launch_bounds__(256) void attn_mfma3(const u16* __restrict__ qkb,
                                                  const u16* __restrict__ vtg,
                                                  u16* __restrict__ opart,
                                                  float* __restrict__ lpart) {
  const int bx = blockIdx.x;
  const int qt = 15 - (bx >> 6);
  const int r6 = bx & 63;
  const int bh = r6 >> 1, half = r6 & 1;
  const int b = bh >> 4, h = bh & 15;
  const int t = threadIdx.x, lane = t & 63, w = t >> 6;
  const int l15 = lane & 15, quad = lane >> 4;

  __shared__ __align__(16) u16 Qs[128 * 64];
  __shared__ __align__(16) u16 Ks[64 * 64];
  __shared__ __align__(16) u16 Vt[64 * 64];
  __shared__ __align__(16) u16 Pa[128 * 72];

  {
    const u16* qb = qkb + ((size_t)(b * SEQ + qt * 128)) * 2048 + h * HDIM;
#pragma unroll
    for (int is = 0; is < 4; ++is) {
      int s = is * 256 + t;
      int row = s >> 3, pos = s & 7;
      int kc = pos ^ (row & 7);
      gload_lds16(qb + (size_t)row * 2048 + kc * 8, &Qs[s * 8]);
    }
  }
  __syncthreads();
  short8 qf[2][2];
#pragma unroll
  for (int qs = 0; qs < 2; ++qs) {
    int qrow = w * 32 + qs * 16 + l15;
#pragma unroll
    for (int hf = 0; hf < 2; ++hf)
      qf[qs][hf] = *(const short8*)&Qs[qrow * 64 + (((hf * 4 + quad) ^ (qrow & 7)) * 8)];
  }

  float rs[2] = {0.f, 0.f};
  floatx4 o_acc[2][4] = {};

  const int kt0 = half ? (qt + 1) : 0;
  const int kt_end = kt0 + qt + 1;
  const int um_end = (kt_end < 2 * qt) ? kt_end : (2 * qt);

#define ATTN_TILE(KT, MASKED)                                                  \
  {                                                                            \
    __syncthreads();                                                           \
    const u16* kb = qkb + ((size_t)(b * SEQ + (KT) * 64)) * 2048 + NEMBD + h * HDIM; \
    const u16* vb = vtg + ((size_t)(bh * 64)) * SEQ + (KT) * 64;               \
    _Pragma("unroll")                                                          \
    for (int is = 0; is < 2; ++is) {                                           \
      int s = is * 256 + t;                                                    \
      int row = s >> 3, pos = s & 7;                                           \
      int kc = pos ^ (row & 7);                                                \
      gload_lds16(kb + (size_t)row * 2048 + kc * 8, &Ks[s * 8]);               \
      gload_lds16(vb + (size_t)row * SEQ + kc * 8, &Vt[s * 8]);                \
    }                                                                          \
    __syncthreads();                                                           \
    floatx4 sacc[2][4];                                                        \
    _Pragma("unroll")                                                          \
    for (int nt = 0; nt < 4; ++nt) {                                           \
      int krow = nt * 16 + l15;                                                \
      short8 kf0 = *(const short8*)&Ks[krow * 64 + ((quad ^ (krow & 7)) * 8)]; \
      short8 kf1 = *(const short8*)&Ks[krow * 64 + (((4 + quad) ^ (krow & 7)) * 8)]; \
      _Pragma("unroll")                                                        \
      for (int qs = 0; qs < 2; ++qs) {                                         \
        floatx4 z = {0.f, 0.f, 0.f, 0.f};                                      \
        z = MFMA16(kf0, qf[qs][0], z);                                         \
        z = MFMA16(kf1, qf[qs][1], z);                                         \
        sacc[qs][nt] = z;                                                      \
      }                                                                        \
    }                                                                          \
    _Pragma("unroll")                                                          \
    for (int qs = 0; qs < 2; ++qs) {                                           \
      const int qg = qt * 128 + w * 32 + qs * 16 + l15;                        \
      const int kb0 = (KT) * 64 + quad * 4;                                    \
      _Pragma("unroll")                                                        \
      for (int nt = 0; nt < 4; ++nt) {                                         \
        ushort4v pk;                                                           \
        _Pragma("unroll")                                                      \
        for (int r = 0; r < 4; ++r) {                                          \
          float p = exp2f(fmaf(sacc[qs][nt][r], SCALE_LOG2E, -8.0f));          \
          if (MASKED && (kb0 + nt * 16 + r) > qg) p = 0.0f;                    \
          rs[qs] += p;                                                         \
          pk[r] = f2bf(p);                                                     \
        }                                                                      \
        *(ushort4v*)&Pa[(w * 32 + qs * 16 + l15) * 72 + nt * 16 + quad * 4] = pk; \
      }                                                                        \
    }                                                                          \
    short8 pf[2][2];                                                           \
    _Pragma("unroll")                                                          \
    for (int qs = 0; qs < 2; ++qs) {                                           \
      const int prow = w * 32 + qs * 16 + l15;                                 \
      pf[qs][0] = *(const short8*)&Pa[prow * 72 + quad * 8];                   \
      pf[qs][1] = *(const short8*)&Pa[prow * 72 + 32 + quad * 8];              \
    }                                                                          \
    _Pragma("unroll")                                                          \
    for (int nt = 0; nt < 4; ++nt) {                                           \
      int drow = nt * 16 + l15;                                                \
      short8 vf0 = *(const short8*)&Vt[drow * 64 + ((quad ^ (drow & 7)) * 8)]; \
      short8 vf1 = *(const short8*)&Vt[drow * 64 + (((4 + quad) ^ (drow & 7)) * 8)]; \
      _Pragma("unroll")                                                        \
      for (int qs = 0; qs < 2; ++qs) {                                         \
        o_acc[qs][nt] = MFMA16(pf[qs][0], vf0, o_acc[qs][nt]);                 \
        o_acc[qs][nt] = MFMA16(pf[qs][1], vf1, o_acc[qs][nt]);                 \
      }                                                                        \
    }                                                                          \
  }

  int kt = kt0;
  for (; kt < um_end; ++kt) ATTN_TILE(kt, 0);
  for (; kt < kt_end; ++kt) ATTN_TILE(kt, 1);
#undef ATTN_TILE

#pragma unroll
  for (int qs = 0; qs < 2; ++qs) {
    rs[qs] += __shfl_xor(rs[qs], 16, 64);
    rs[qs] += __shfl_xor(rs[qs], 32, 64);
    if (quad == 0)
      lpart[((size_t)half * 32 + bh) * SEQ + qt * 128 + w * 32 + qs * 16 + l15] = rs[qs];
  }
  u16* ob = opart + (size_t)half * BT * NEMBD;
#pragma unroll
  for (int qs = 0; qs < 2; ++qs)
#pragma unroll
    for (int nt = 0; nt < 4; ++nt)
#pragma unroll
      for (int r = 0; r < 4; ++r) {
        size_t tok = (size_t)(b * SEQ + qt * 128 + w * 32 + qs * 16 + quad * 4 + r);
        ob[tok * NEMBD + h * HDIM + nt * 16 + l15] = f2bf(o_acc[qs][nt][r]);
      }
}

// ---------------------------------------------------------------------------
// Combine split-K partials: yb = (O0 + O1) / (l0 + l1), bf16.
// ---------------------------------------------------------------------------
__global__ __launch_bounds__(256) void combine(const u16* __restrict__ opart,
                                               const float* __restrict__ lpart,
                                               u16* __restrict__ yb) {
  int idx = (blockIdx.x * 256 + threadIdx.x) * 4;
  int tok = idx >> 10, c = idx & 1023;
  int b = tok >> 11, q = tok & (SEQ - 1), h = c >> 6;
  float l = lpart[(size_t)(b * 16 + h) * SEQ + q] +
            lpart[(size_t)(32 + b * 16 + h) * SEQ + q];
  float inv = 1.0f / l;
  ushort4v o0 = *(const ushort4v*)&opart[idx];
  ushort4v o1 = *(const ushort4v*)&opart[(size_t)BT * NEMBD + idx];
  ushort4v yo;
#pragma unroll
  for (int j = 0; j < 4; ++j) {
    float f0 = bf2f(o0[j]);
    float f1 = bf2f(o1[j]);
    yo[j] = f2bf((f0 + f1) * inv);
  }
  *(ushort4v*)&yb[idx] = yo;
}

// ---------------------------------------------------------------------------
// GEMM2: out(fp32) = yb @ w_proj^T. 128x64 tile, BK=64 swizzled,
// operand-swapped -> float4 stores. 512 blocks.
// ---------------------------------------------------------------------------
__global__ __launch_bounds__(256) void gemm_out(const u16* __restrict__ A,
                                                const u16* __restrict__ B,
                                                float* __restrict__ C) {
  __shared__ __align__(16) u16 As[128 * 64];  // 16 KB
  __shared__ __align__(16) u16 Bs[64 * 64];   //  8 KB
  const int t = threadIdx.x;
  const int lane = t & 63, w = t >> 6;
  const int l15 = lane & 15, quad = lane >> 4;
  const int wm = w >> 1, wn = w & 1;
  const int m0 = blockIdx.y * 128, n0 = blockIdx.x * 64;

  floatx4 acc[4][2] = {};

  for (int k0 = 0; k0 < NEMBD; k0 += 64) {
    __syncthreads();
#pragma unroll
    for (int is = 0; is < 4; ++is) {
      int s = is * 256 + t;
      int row = s >> 3, pos = s & 7;
      int kc = pos ^ (row & 7);
      gload_lds16(A + (size_t)(m0 + row) * NEMBD + k0 + kc * 8, &As[s * 8]);
    }
#pragma unroll
    for (int is = 0; is < 2; ++is) {
      int s = is * 256 + t;
      int row = s >> 3, pos = s & 7;
      int kc = pos ^ (row & 7);
      gload_lds16(B + (size_t)(n0 + row) * NEMBD + k0 + kc * 8, &Bs[s * 8]);
    }
    __syncthreads();
#pragma unroll
    for (int kh = 0; kh < 2; ++kh) {
      short8 af[4], bfr[2];
#pragma unroll
      for (int mt = 0; mt < 4; ++mt) {
        int row = wm * 64 + mt * 16 + l15;
        af[mt] = *(const short8*)&As[row * 64 + (((kh * 4 + quad) ^ (row & 7)) * 8)];
      }
#pragma unroll
      for (int nt = 0; nt < 2; ++nt) {
        int row = wn * 32 + nt * 16 + l15;
        bfr[nt] = *(const short8*)&Bs[row * 64 + (((kh * 4 + quad) ^ (row & 7)) * 8)];
      }
#pragma unroll
      for (int mt = 0; mt < 4; ++mt)
#pragma unroll
        for (int nt = 0; nt < 2; ++nt)
          acc[mt][nt] = MFMA16(bfr[nt], af[mt], acc[mt][nt]);   // D[n][m]
    }
  }

  // swapped: rows = n (quad*4+r), cols = token (l15) -> float4 stores
#pragma unroll
  for (int mt = 0; mt < 4; ++mt) {
    size_t token = (size_t)(m0 + wm * 64 + mt * 16 + l15);
#pragma unroll
    for (int nt = 0; nt < 2; ++nt) {
      int nc = n0 + wn * 32 + nt * 16 + quad * 4;
      float4 v = make_float4(acc[mt][nt][0], acc[mt][nt][1],
                             acc[mt][nt][2], acc[mt][nt][3]);
      *(float4*)&C[token * NEMBD + nc] = v;
    }
  }
}

// ---------------------------------------------------------------------------
extern "C" void kernel_launch(void* const* d_in, const int* in_sizes, int n_in,
                              void* d_out, int out_size, void* d_ws, size_t ws_size,
                              hipStream_t stream) {
  const float* x      = (const float*)d_in[0];
  const float* w_attn = (const float*)d_in[1];
  const float* w_proj = (const float*)d_in[2];
  float* out = (float*)d_out;

  // Workspace (u16 units). opart ALIASES xb+wab (dead after gemm_qkv).
  u16* base  = (u16*)d_ws;
  u16* opart = base;                       // 2*4096*1024 u16 = 16 MB
  u16* xb    = base;                       // alias
  u16* wab   = base + 4194304;             // alias
  u16* wpb   = base + 8388608;             // 2 MB
  u16* qkb   = base + 9437184;             // 16 MB
  u16* vtg   = base + 17825792;            // 8 MB
  u16* yb    = base + 22020096;            // 8 MB
  float* lpart = (float*)(base + 26214400);  // 0.5 MB

  cvt_all<<<(N_X + N_WA + N_WP) / 2048, 256, 0, stream>>>(x, w_attn, w_proj, xb, wab, wpb);

  gemm_qkv<<<dim3(QKV_LD / 128, BT / 128), 256, 0, stream>>>(xb, wab, qkb, vtg);

  attn_mfma3<<<dim3((SEQ / 128) * BSZ * NHEAD * 2), 256, 0, stream>>>(qkb, vtg, opart, lpart);

  combine<<<(BT * NEMBD) / 1024, 256, 0, stream>>>(opart, lpart, yb);

  gemm_out<<<dim3(NEMBD / 64, BT / 128), 256, 0, stream>>>(yb, wpb, out);
}

// Round 9
// 199.183 us; speedup vs baseline: 1.1904x; 1.1904x over previous
//
#include <hip/hip_runtime.h>

// CausalSelfAttention: B=2, T=2048, C=1024, H=16, D=64
// bf16 MFMA; BK=64 XOR-swizzled GEMMs w/ operand-swapped epilogues;
// S^T-form flash attention, fixed-C softmax, 2-way split-K,
//   K/V double-buffered in LDS (buf1 aliases dead Q tile) -> 1 barrier/iter.
// Standalone combine kernel (R7 fused-combine recomputed per n-block: regressed).
// NOTES: __launch_bounds__(256,4) on GEMMs spills the acc tile (R6: 549 MB
// scratch writes, 4.4x). Register-A frags in gemm_qkv regressed (R8: scattered
// per-lane loads in MFMA critical path, MfmaUtil 16->10.7%). Keep LDS staging.
#define BSZ 2
#define SEQ 2048
#define NEMBD 1024
#define NHEAD 16
#define HDIM 64
#define BT (BSZ * SEQ)          // 4096
#define QKV_LD (3 * NEMBD)      // 3072
#define SCALE_LOG2E 0.1803368665f   // (1/sqrt(64)) * log2(e)

typedef unsigned short u16;
typedef __attribute__((ext_vector_type(8))) short short8;     // 8 bf16 (MFMA A/B frag)
typedef __attribute__((ext_vector_type(4))) float floatx4;    // MFMA C/D frag
typedef __attribute__((ext_vector_type(4))) unsigned short ushort4v;

#define MFMA16(a, b, c) __builtin_amdgcn_mfma_f32_16x16x32_bf16(a, b, c, 0, 0, 0)

__device__ __forceinline__ void gload_lds16(const void* g, void* l) {
  __builtin_amdgcn_global_load_lds(
      (const __attribute__((address_space(1))) unsigned int*)(g),
      (__attribute__((address_space(3))) unsigned int*)(l), 16, 0, 0);
}

__device__ __forceinline__ u16 f2bf(float f) {  // fp32 -> bf16 RNE
  unsigned int u = __builtin_bit_cast(unsigned int, f);
  u += 0x7FFFu + ((u >> 16) & 1u);
  return (u16)(u >> 16);
}

__device__ __forceinline__ float bf2f(u16 v) {
  return __builtin_bit_cast(float, (unsigned)v << 16);
}

// ---------------------------------------------------------------------------
// Fused fp32->bf16 conversion of x, w_attn, w_proj in one launch.
// ---------------------------------------------------------------------------
#define N_X  (BT * NEMBD)          // 4194304
#define N_WA (QKV_LD * NEMBD)      // 3145728
#define N_WP (NEMBD * NEMBD)       // 1048576
__global__ __launch_bounds__(256) void cvt_all(const float* __restrict__ x,
                                               const float* __restrict__ wa,
                                               const float* __restrict__ wp,
                                               u16* __restrict__ xb,
                                               u16* __restrict__ wab,
                                               u16* __restrict__ wpb) {
  int i = (blockIdx.x * 256 + threadIdx.x) * 8;
  const float* src;
  u16* dst;
  if (i < N_X)            { src = x + i;              dst = xb + i; }
  else if (i < N_X + N_WA){ src = wa + (i - N_X);     dst = wab + (i - N_X); }
  else                    { src = wp + (i - N_X - N_WA); dst = wpb + (i - N_X - N_WA); }
  float4 a = *(const float4*)(src);
  float4 b = *(const float4*)(src + 4);
  short8 o;
  o[0] = (short)f2bf(a.x); o[1] = (short)f2bf(a.y);
  o[2] = (short)f2bf(a.z); o[3] = (short)f2bf(a.w);
  o[4] = (short)f2bf(b.x); o[5] = (short)f2bf(b.y);
  o[6] = (short)f2bf(b.z); o[7] = (short)f2bf(b.w);
  *(short8*)(dst) = o;
}

// ---------------------------------------------------------------------------
// GEMM1: qkv = x @ w_attn^T. 128x128 tile, BK=64, XOR-swizzled LDS (R5 form).
// LDS element [row][c] at row*64 + (((c>>3) ^ (row&7))*8 + (c&7)).
// n0 < 2048 (Q,K): operand-SWAPPED MFMA -> lane packs 4 consecutive n.
// n0 >= 2048 (V): normal order -> lane packs 4 consecutive tokens -> vtg.
// ---------------------------------------------------------------------------
__global__ __launch_bounds__(256) void gemm_qkv(const u16* __restrict__ A,
                                                const u16* __restrict__ B,
                                                u16* __restrict__ qkb,
                                                u16* __restrict__ vtg) {
  __shared__ __align__(16) u16 As[128 * 64];  // 16 KB
  __shared__ __align__(16) u16 Bs[128 * 64];  // 16 KB
  const int t = threadIdx.x;
  const int lane = t & 63, w = t >> 6;
  const int l15 = lane & 15, quad = lane >> 4;
  const int wm = w >> 1, wn = w & 1;
  const int m0 = blockIdx.y * 128, n0 = blockIdx.x * 128;
  const int is_v = (n0 >= 2 * NEMBD);

  floatx4 acc[4][4] = {};

  for (int k0 = 0; k0 < NEMBD; k0 += 64) {
    __syncthreads();
#pragma unroll
    for (int is = 0; is < 4; ++is) {
      int s = is * 256 + t;
      int row = s >> 3, pos = s & 7;
      int kc = pos ^ (row & 7);
      gload_lds16(A + (size_t)(m0 + row) * NEMBD + k0 + kc * 8, &As[s * 8]);
      gload_lds16(B + (size_t)(n0 + row) * NEMBD + k0 + kc * 8, &Bs[s * 8]);
    }
    __syncthreads();
#pragma unroll
    for (int kh = 0; kh < 2; ++kh) {
      short8 af[4], bfr[4];
#pragma unroll
      for (int mt = 0; mt < 4; ++mt) {
        int row = wm * 64 + mt * 16 + l15;
        af[mt] = *(const short8*)&As[row * 64 + (((kh * 4 + quad) ^ (row & 7)) * 8)];
      }
#pragma unroll
      for (int nt = 0; nt < 4; ++nt) {
        int row = wn * 64 + nt * 16 + l15;
        bfr[nt] = *(const short8*)&Bs[row * 64 + (((kh * 4 + quad) ^ (row & 7)) * 8)];
      }
      if (is_v) {
#pragma unroll
        for (int mt = 0; mt < 4; ++mt)
#pragma unroll
          for (int nt = 0; nt < 4; ++nt)
            acc[mt][nt] = MFMA16(af[mt], bfr[nt], acc[mt][nt]);   // D[m][n]
      } else {
#pragma unroll
        for (int mt = 0; mt < 4; ++mt)
#pragma unroll
          for (int nt = 0; nt < 4; ++nt)
            acc[mt][nt] = MFMA16(bfr[nt], af[mt], acc[mt][nt]);   // D[n][m]
      }
    }
  }

  if (is_v) {
#pragma unroll
    for (int mt = 0; mt < 4; ++mt)
#pragma unroll
      for (int nt = 0; nt < 4; ++nt) {
        int hd = n0 + wn * 64 + nt * 16 + l15 - 2 * NEMBD;
        int token = m0 + wm * 64 + mt * 16 + quad * 4;
        int b = token >> 11, tp = token & (SEQ - 1);
        ushort4v pk;
#pragma unroll
        for (int r = 0; r < 4; ++r) pk[r] = f2bf(acc[mt][nt][r]);
        *(ushort4v*)&vtg[((size_t)(b * NEMBD + hd)) * SEQ + tp] = pk;
      }
  } else {
#pragma unroll
    for (int mt = 0; mt < 4; ++mt) {
      size_t token = (size_t)(m0 + wm * 64 + mt * 16 + l15);
#pragma unroll
      for (int nt = 0; nt < 4; ++nt) {
        int nc = n0 + wn * 64 + nt * 16 + quad * 4;
        ushort4v pk;
#pragma unroll
        for (int r = 0; r < 4; ++r) pk[r] = f2bf(acc[mt][nt][r]);
        *(ushort4v*)&qkb[token * 2048 + nc] = pk;
      }
    }
  }
}

// ---------------------------------------------------------------------------
// Flash attention (causal), S^T form, fixed-C softmax (C=8), 2-way split-K.
// K/V double-buffered: buf1 aliases the Q tile (dead after prologue) -> LDS
// stays 50 KB (3 blocks/CU), ONE barrier per K-tile, staging latency hidden
// behind compute. Pa is wave-local (rows w*32..w*32+31) -> needs no barrier.
// ---------------------------------------------------------------------------
__global__ __launch_bounds__(256) void attn_mfma4(const u16* __restrict__ qkb,
                                                  const u16* __restrict__ vtg,
                                                  u16* __restrict__ opart,
                                                  float* __restrict__ lpart) {
  const int bx = blockIdx.x;
  const int qt = 15 - (bx >> 6);
  const int r6 = bx & 63;
  const int bh = r6 >> 1, half = r6 & 1;
  const int b = bh >> 4, h = bh & 15;
  const int t = threadIdx.x, lane = t & 63, w = t >> 6;
  const int l15 = lane & 15, quad = lane >> 4;

  __shared__ __align__(16) u16 S[25600];  // 50 KB
  u16* Qs  = S;           // 128x64 swizzled (prologue only; becomes KV buf1)
  u16* KV0 = S + 8192;    // Ks @ +0 (64x64), Vt @ +4096 (64x64)
  u16* KV1 = S;           // aliases Qs
  u16* Pa  = S + 16384;   // 128x72

  const int kt0 = half ? (qt + 1) : 0;
  const int nkt = qt + 1;

  // ---- stage Q ----
  {
    const u16* qb = qkb + ((size_t)(b * SEQ + qt * 128)) * 2048 + h * HDIM;
#pragma unroll
    for (int is = 0; is < 4; ++is) {
      int s = is * 256 + t;
      int row = s >> 3, pos = s & 7;
      int kc = pos ^ (row & 7);
      gload_lds16(qb + (size_t)row * 2048 + kc * 8, &Qs[s * 8]);
    }
  }

#define STAGE_KV(KT, BUF)                                                      \
  {                                                                            \
    const u16* kb_ = qkb + ((size_t)(b * SEQ + (KT) * 64)) * 2048 + NEMBD + h * HDIM; \
    const u16* vb_ = vtg + ((size_t)(bh * 64)) * SEQ + (KT) * 64;              \
    _Pragma("unroll")                                                          \
    for (int is = 0; is < 2; ++is) {                                           \
      int s = is * 256 + t;                                                    \
      int row = s >> 3, pos = s & 7;                                           \
      int kc = pos ^ (row & 7);                                                \
      gload_lds16(kb_ + (size_t)row * 2048 + kc * 8, &(BUF)[s * 8]);           \
      gload_lds16(vb_ + (size_t)row * SEQ + kc * 8, &(BUF)[4096 + s * 8]);     \
    }                                                                          \
  }

  STAGE_KV(kt0, KV0);
  __syncthreads();  // Q + kt0 staged

  short8 qf[2][2];
#pragma unroll
  for (int qs = 0; qs < 2; ++qs) {
    int qrow = w * 32 + qs * 16 + l15;
#pragma unroll
    for (int hf = 0; hf < 2; ++hf)
      qf[qs][hf] = *(const short8*)&Qs[qrow * 64 + (((hf * 4 + quad) ^ (qrow & 7)) * 8)];
  }
  __syncthreads();  // all qf reads done before KV1(=Qs) is overwritten

  float rs[2] = {0.f, 0.f};
  floatx4 o_acc[2][4] = {};

#define COMPUTE_TILE(BUF, KT, MASKED)                                          \
  {                                                                            \
    floatx4 sacc[2][4];                                                        \
    _Pragma("unroll")                                                          \
    for (int nt = 0; nt < 4; ++nt) {                                           \
      int krow = nt * 16 + l15;                                                \
      short8 kf0 = *(const short8*)&(BUF)[krow * 64 + ((quad ^ (krow & 7)) * 8)]; \
      short8 kf1 = *(const short8*)&(BUF)[krow * 64 + (((4 + quad) ^ (krow & 7)) * 8)]; \
      _Pragma("unroll")                                                        \
      for (int qs = 0; qs < 2; ++qs) {                                         \
        floatx4 z = {0.f, 0.f, 0.f, 0.f};                                      \
        z = MFMA16(kf0, qf[qs][0], z);                                         \
        z = MFMA16(kf1, qf[qs][1], z);                                         \
        sacc[qs][nt] = z;                                                      \
      }                                                                        \
    }                                                                          \
    _Pragma("unroll")                                                          \
    for (int qs = 0; qs < 2; ++qs) {                                           \
      const int qg = qt * 128 + w * 32 + qs * 16 + l15;                        \
      const int kb0 = (KT) * 64 + quad * 4;                                    \
      _Pragma("unroll")                                                        \
      for (int nt = 0; nt < 4; ++nt) {                                         \
        ushort4v pk;                                                           \
        _Pragma("unroll")                                                      \
        for (int r = 0; r < 4; ++r) {                                          \
          float p = exp2f(fmaf(sacc[qs][nt][r], SCALE_LOG2E, -8.0f));          \
          if (MASKED && (kb0 + nt * 16 + r) > qg) p = 0.0f;                    \
          rs[qs] += p;                                                         \
          pk[r] = f2bf(p);                                                     \
        }                                                                      \
        *(ushort4v*)&Pa[(w * 32 + qs * 16 + l15) * 72 + nt * 16 + quad * 4] = pk; \
      }                                                                        \
    }                                                                          \
    short8 pf[2][2];                                                           \
    _Pragma("unroll")                                                          \
    for (int qs = 0; qs < 2; ++qs) {                                           \
      const int prow = w * 32 + qs * 16 + l15;                                 \
      pf[qs][0] = *(const short8*)&Pa[prow * 72 + quad * 8];                   \
      pf[qs][1] = *(const short8*)&Pa[prow * 72 + 32 + quad * 8];              \
    }                                                                          \
    _Pragma("unroll")                                                          \
    for (int nt = 0; nt < 4; ++nt) {                                           \
      int drow = nt * 16 + l15;                                                \
      short8 vf0 = *(const short8*)&(BUF)[4096 + drow * 64 + ((quad ^ (drow & 7)) * 8)]; \
      short8 vf1 = *(const short8*)&(BUF)[4096 + drow * 64 + (((4 + quad) ^ (drow & 7)) * 8)]; \
      _Pragma("unroll")                                                        \
      for (int qs = 0; qs < 2; ++qs) {                                         \
        o_acc[qs][nt] = MFMA16(pf[qs][0], vf0, o_acc[qs][nt]);                 \
        o_acc[qs][nt] = MFMA16(pf[qs][1], vf1, o_acc[qs][nt]);                 \
      }                                                                        \
    }                                                                          \
  }

  for (int i = 0; i < nkt; ++i) {
    const int kt = kt0 + i;
    u16* cur = (i & 1) ? KV1 : KV0;
    u16* nxt = (i & 1) ? KV0 : KV1;
    if (i + 1 < nkt) STAGE_KV(kt0 + i + 1, nxt);   // async; drained at iter-end barrier
    if (kt >= 2 * qt) { COMPUTE_TILE(cur, kt, 1); }
    else              { COMPUTE_TILE(cur, kt, 0); }
    __syncthreads();  // single barrier: next staging visible + cur reads done
  }
#undef COMPUTE_TILE
#undef STAGE_KV

  // ---- epilogue: reduce l over quads, store partials ----
#pragma unroll
  for (int qs = 0; qs < 2; ++qs) {
    rs[qs] += __shfl_xor(rs[qs], 16, 64);
    rs[qs] += __shfl_xor(rs[qs], 32, 64);
    if (quad == 0)
      lpart[((size_t)half * 32 + bh) * SEQ + qt * 128 + w * 32 + qs * 16 + l15] = rs[qs];
  }
  u16* ob = opart + (size_t)half * BT * NEMBD;
#pragma unroll
  for (int qs = 0; qs < 2; ++qs)
#pragma unroll
    for (int nt = 0; nt < 4; ++nt)
#pragma unroll
      for (int r = 0; r < 4; ++r) {
        size_t tok = (size_t)(b * SEQ + qt * 128 + w * 32 + qs * 16 + quad * 4 + r);
        ob[tok * NEMBD + h * HDIM + nt * 16 + l15] = f2bf(o_acc[qs][nt][r]);
      }
}

// ---------------------------------------------------------------------------
// Combine split-K partials: yb = (O0 + O1) / (l0 + l1), bf16.
// ---------------------------------------------------------------------------
__global__ __launch_bounds__(256) void combine(const u16* __restrict__ opart,
                                               const float* __restrict__ lpart,
                                               u16* __restrict__ yb) {
  int idx = (blockIdx.x * 256 + threadIdx.x) * 4;
  int tok = idx >> 10, c = idx & 1023;
  int b = tok >> 11, q = tok & (SEQ - 1), h = c >> 6;
  float l = lpart[(size_t)(b * 16 + h) * SEQ + q] +
            lpart[(size_t)(32 + b * 16 + h) * SEQ + q];
  float inv = 1.0f / l;
  ushort4v o0 = *(const ushort4v*)&opart[idx];
  ushort4v o1 = *(const ushort4v*)&opart[(size_t)BT * NEMBD + idx];
  ushort4v yo;
#pragma unroll
  for (int j = 0; j < 4; ++j) {
    float f0 = bf2f(o0[j]);
    float f1 = bf2f(o1[j]);
    yo[j] = f2bf((f0 + f1) * inv);
  }
  *(ushort4v*)&yb[idx] = yo;
}

// ---------------------------------------------------------------------------
// GEMM2: out(fp32) = yb @ w_proj^T. 128x64 tile, BK=64 swizzled,
// operand-swapped -> float4 stores. 512 blocks.
// ---------------------------------------------------------------------------
__global__ __launch_bounds__(256) void gemm_out(const u16* __restrict__ A,
                                                const u16* __restrict__ B,
                                                float* __restrict__ C) {
  __shared__ __align__(16) u16 As[128 * 64];  // 16 KB
  __shared__ __align__(16) u16 Bs[64 * 64];   //  8 KB
  const int t = threadIdx.x;
  const int lane = t & 63, w = t >> 6;
  const int l15 = lane & 15, quad = lane >> 4;
  const int wm = w >> 1, wn = w & 1;
  const int m0 = blockIdx.y * 128, n0 = blockIdx.x * 64;

  floatx4 acc[4][2] = {};

  for (int k0 = 0; k0 < NEMBD; k0 += 64) {
    __syncthreads();
#pragma unroll
    for (int is = 0; is < 4; ++is) {
      int s = is * 256 + t;
      int row = s >> 3, pos = s & 7;
      int kc = pos ^ (row & 7);
      gload_lds16(A + (size_t)(m0 + row) * NEMBD + k0 + kc * 8, &As[s * 8]);
    }
#pragma unroll
    for (int is = 0; is < 2; ++is) {
      int s = is * 256 + t;
      int row = s >> 3, pos = s & 7;
      int kc = pos ^ (row & 7);
      gload_lds16(B + (size_t)(n0 + row) * NEMBD + k0 + kc * 8, &Bs[s * 8]);
    }
    __syncthreads();
#pragma unroll
    for (int kh = 0; kh < 2; ++kh) {
      short8 af[4], bfr[2];
#pragma unroll
      for (int mt = 0; mt < 4; ++mt) {
        int row = wm * 64 + mt * 16 + l15;
        af[mt] = *(const short8*)&As[row * 64 + (((kh * 4 + quad) ^ (row & 7)) * 8)];
      }
#pragma unroll
      for (int nt = 0; nt < 2; ++nt) {
        int row = wn * 32 + nt * 16 + l15;
        bfr[nt] = *(const short8*)&Bs[row * 64 + (((kh * 4 + quad) ^ (row & 7)) * 8)];
      }
#pragma unroll
      for (int mt = 0; mt < 4; ++mt)
#pragma unroll
        for (int nt = 0; nt < 2; ++nt)
          acc[mt][nt] = MFMA16(bfr[nt], af[mt], acc[mt][nt]);   // D[n][m]
    }
  }

#pragma unroll
  for (int mt = 0; mt < 4; ++mt) {
    size_t token = (size_t)(m0 + wm * 64 + mt * 16 + l15);
#pragma unroll
    for (int nt = 0; nt < 2; ++nt) {
      int nc = n0 + wn * 32 + nt * 16 + quad * 4;
      float4 v = make_float4(acc[mt][nt][0], acc[mt][nt][1],
                             acc[mt][nt][2], acc[mt][nt][3]);
      *(float4*)&C[token * NEMBD + nc] = v;
    }
  }
}

// ---------------------------------------------------------------------------
extern "C" void kernel_launch(void* const* d_in, const int* in_sizes, int n_in,
                              void* d_out, int out_size, void* d_ws, size_t ws_size,
                              hipStream_t stream) {
  const float* x      = (const float*)d_in[0];
  const float* w_attn = (const float*)d_in[1];
  const float* w_proj = (const float*)d_in[2];
  float* out = (float*)d_out;

  // Workspace (u16 units). opart ALIASES xb+wab (dead after gemm_qkv).
  u16* base  = (u16*)d_ws;
  u16* opart = base;                       // 2*4096*1024 u16 = 16 MB
  u16* xb    = base;                       // alias
  u16* wab   = base + 4194304;             // alias
  u16* wpb   = base + 8388608;             // 2 MB
  u16* qkb   = base + 9437184;             // 16 MB
  u16* vtg   = base + 17825792;            // 8 MB
  u16* yb    = base + 22020096;            // 8 MB
  float* lpart = (float*)(base + 26214400);  // 0.5 MB

  cvt_all<<<(N_X + N_WA + N_WP) / 2048, 256, 0, stream>>>(x, w_attn, w_proj, xb, wab, wpb);

  gemm_qkv<<<dim3(QKV_LD / 128, BT / 128), 256, 0, stream>>>(xb, wab, qkb, vtg);

  attn_mfma4<<<dim3((SEQ / 128) * BSZ * NHEAD * 2), 256, 0, stream>>>(qkb, vtg, opart, lpart);

  combine<<<(BT * NEMBD) / 1024, 256, 0, stream>>>(opart, lpart, yb);

  gemm_out<<<dim3(NEMBD / 64, BT / 128), 256, 0, stream>>>(yb, wpb, out);
}

// Round 10
// 187.594 us; speedup vs baseline: 1.2639x; 1.0618x over previous
//
#include <hip/hip_runtime.h>

// CausalSelfAttention: B=2, T=2048, C=1024, H=16, D=64
// bf16 MFMA; BK=64 XOR-swizzled GEMMs w/ operand-swapped epilogues.
// gemm_qkv: register-prefetch double-buffer (tile k+1 -> VGPRs during compute k).
// gemm_out: async-LDS ping-pong (48 KB, 1 barrier/iter) - attn_mfma4's pattern.
// S^T-form flash attention, fixed-C softmax, 2-way split-K, K/V dbuf via Q-alias.
// NOTES: __launch_bounds__(256,4) spills acc (R6). Per-lane register A-frags
// without LDS regressed (R8). Fused combine in gemm_out regressed (R7).
#define BSZ 2
#define SEQ 2048
#define NEMBD 1024
#define NHEAD 16
#define HDIM 64
#define BT (BSZ * SEQ)          // 4096
#define QKV_LD (3 * NEMBD)      // 3072
#define SCALE_LOG2E 0.1803368665f   // (1/sqrt(64)) * log2(e)

typedef unsigned short u16;
typedef __attribute__((ext_vector_type(8))) short short8;     // 8 bf16 (MFMA A/B frag)
typedef __attribute__((ext_vector_type(4))) float floatx4;    // MFMA C/D frag
typedef __attribute__((ext_vector_type(4))) unsigned short ushort4v;

#define MFMA16(a, b, c) __builtin_amdgcn_mfma_f32_16x16x32_bf16(a, b, c, 0, 0, 0)

__device__ __forceinline__ void gload_lds16(const void* g, void* l) {
  __builtin_amdgcn_global_load_lds(
      (const __attribute__((address_space(1))) unsigned int*)(g),
      (__attribute__((address_space(3))) unsigned int*)(l), 16, 0, 0);
}

__device__ __forceinline__ u16 f2bf(float f) {  // fp32 -> bf16 RNE
  unsigned int u = __builtin_bit_cast(unsigned int, f);
  u += 0x7FFFu + ((u >> 16) & 1u);
  return (u16)(u >> 16);
}

__device__ __forceinline__ float bf2f(u16 v) {
  return __builtin_bit_cast(float, (unsigned)v << 16);
}

// ---------------------------------------------------------------------------
// Fused fp32->bf16 conversion of x, w_attn, w_proj in one launch.
// ---------------------------------------------------------------------------
#define N_X  (BT * NEMBD)          // 4194304
#define N_WA (QKV_LD * NEMBD)      // 3145728
#define N_WP (NEMBD * NEMBD)       // 1048576
__global__ __launch_bounds__(256) void cvt_all(const float* __restrict__ x,
                                               const float* __restrict__ wa,
                                               const float* __restrict__ wp,
                                               u16* __restrict__ xb,
                                               u16* __restrict__ wab,
                                               u16* __restrict__ wpb) {
  int i = (blockIdx.x * 256 + threadIdx.x) * 8;
  const float* src;
  u16* dst;
  if (i < N_X)            { src = x + i;              dst = xb + i; }
  else if (i < N_X + N_WA){ src = wa + (i - N_X);     dst = wab + (i - N_X); }
  else                    { src = wp + (i - N_X - N_WA); dst = wpb + (i - N_X - N_WA); }
  float4 a = *(const float4*)(src);
  float4 b = *(const float4*)(src + 4);
  short8 o;
  o[0] = (short)f2bf(a.x); o[1] = (short)f2bf(a.y);
  o[2] = (short)f2bf(a.z); o[3] = (short)f2bf(a.w);
  o[4] = (short)f2bf(b.x); o[5] = (short)f2bf(b.y);
  o[6] = (short)f2bf(b.z); o[7] = (short)f2bf(b.w);
  *(short8*)(dst) = o;
}

// ---------------------------------------------------------------------------
// GEMM1: qkv = x @ w_attn^T. 128x128 tile, BK=64, XOR-swizzled LDS.
// Register-prefetch dbuf: tile k+1 loaded into VGPRs during compute of k;
// ds_write after read-done barrier; second barrier is lgkm-only (cheap).
// n0 < 2048 (Q,K): operand-SWAPPED MFMA -> lane packs 4 consecutive n.
// n0 >= 2048 (V): normal order -> lane packs 4 consecutive tokens -> vtg.
// ---------------------------------------------------------------------------
__global__ __launch_bounds__(256) void gemm_qkv(const u16* __restrict__ A,
                                                const u16* __restrict__ B,
                                                u16* __restrict__ qkb,
                                                u16* __restrict__ vtg) {
  __shared__ __align__(16) u16 As[128 * 64];  // 16 KB
  __shared__ __align__(16) u16 Bs[128 * 64];  // 16 KB
  const int t = threadIdx.x;
  const int lane = t & 63, w = t >> 6;
  const int l15 = lane & 15, quad = lane >> 4;
  const int wm = w >> 1, wn = w & 1;
  const int m0 = blockIdx.y * 128, n0 = blockIdx.x * 128;
  const int is_v = (n0 >= 2 * NEMBD);

  // staging geometry: s = is*256 + t; row = is*32 + (t>>3); pos = t&7;
  // kc = pos ^ (row&7) = (t&7) ^ ((t>>3)&7)  (is-independent: 32 ≡ 0 mod 8)
  const int srow8 = t >> 3;
  const int kc = (t & 7) ^ (srow8 & 7);
  const u16* gA = A + (size_t)(m0 + srow8) * NEMBD + kc * 8;
  const u16* gB = B + (size_t)(n0 + srow8) * NEMBD + kc * 8;

  floatx4 acc[4][4] = {};
  short8 ra[4], rb[4];

#define QKV_LOAD(K0)                                                           \
  { _Pragma("unroll")                                                          \
    for (int is = 0; is < 4; ++is) {                                           \
      ra[is] = *(const short8*)(gA + (size_t)(is * 32) * NEMBD + (K0));        \
      rb[is] = *(const short8*)(gB + (size_t)(is * 32) * NEMBD + (K0));        \
    } }
#define QKV_WRITE()                                                            \
  { _Pragma("unroll")                                                          \
    for (int is = 0; is < 4; ++is) {                                           \
      *(short8*)&As[(is * 256 + t) * 8] = ra[is];                              \
      *(short8*)&Bs[(is * 256 + t) * 8] = rb[is];                              \
    } }

  QKV_LOAD(0);
  QKV_WRITE();
  __syncthreads();

  for (int k0 = 0; k0 < NEMBD; k0 += 64) {
    const int more = (k0 + 64 < NEMBD);
    if (more) QKV_LOAD(k0 + 64);   // latency overlaps the MFMA phase below
#pragma unroll
    for (int kh = 0; kh < 2; ++kh) {
      short8 af[4], bfr[4];
#pragma unroll
      for (int mt = 0; mt < 4; ++mt) {
        int row = wm * 64 + mt * 16 + l15;
        af[mt] = *(const short8*)&As[row * 64 + (((kh * 4 + quad) ^ (row & 7)) * 8)];
      }
#pragma unroll
      for (int nt = 0; nt < 4; ++nt) {
        int row = wn * 64 + nt * 16 + l15;
        bfr[nt] = *(const short8*)&Bs[row * 64 + (((kh * 4 + quad) ^ (row & 7)) * 8)];
      }
      if (is_v) {
#pragma unroll
        for (int mt = 0; mt < 4; ++mt)
#pragma unroll
          for (int nt = 0; nt < 4; ++nt)
            acc[mt][nt] = MFMA16(af[mt], bfr[nt], acc[mt][nt]);   // D[m][n]
      } else {
#pragma unroll
        for (int mt = 0; mt < 4; ++mt)
#pragma unroll
          for (int nt = 0; nt < 4; ++nt)
            acc[mt][nt] = MFMA16(bfr[nt], af[mt], acc[mt][nt]);   // D[n][m]
      }
    }
    __syncthreads();               // all waves done reading tile k0
    if (more) {
      QKV_WRITE();                 // vmcnt wait here (loads had full compute to land)
      __syncthreads();             // tile k0+64 visible (lgkm-only drain)
    }
  }
#undef QKV_LOAD
#undef QKV_WRITE

  if (is_v) {
#pragma unroll
    for (int mt = 0; mt < 4; ++mt)
#pragma unroll
      for (int nt = 0; nt < 4; ++nt) {
        int hd = n0 + wn * 64 + nt * 16 + l15 - 2 * NEMBD;
        int token = m0 + wm * 64 + mt * 16 + quad * 4;
        int b = token >> 11, tp = token & (SEQ - 1);
        ushort4v pk;
#pragma unroll
        for (int r = 0; r < 4; ++r) pk[r] = f2bf(acc[mt][nt][r]);
        *(ushort4v*)&vtg[((size_t)(b * NEMBD + hd)) * SEQ + tp] = pk;
      }
  } else {
#pragma unroll
    for (int mt = 0; mt < 4; ++mt) {
      size_t token = (size_t)(m0 + wm * 64 + mt * 16 + l15);
#pragma unroll
      for (int nt = 0; nt < 4; ++nt) {
        int nc = n0 + wn * 64 + nt * 16 + quad * 4;
        ushort4v pk;
#pragma unroll
        for (int r = 0; r < 4; ++r) pk[r] = f2bf(acc[mt][nt][r]);
        *(ushort4v*)&qkb[token * 2048 + nc] = pk;
      }
    }
  }
}

// ---------------------------------------------------------------------------
// Flash attention (causal), S^T form, fixed-C softmax (C=8), 2-way split-K.
// K/V double-buffered (buf1 aliases dead Q tile) -> 1 barrier per K-tile.
// ---------------------------------------------------------------------------
__global__ __launch_bounds__(256) void attn_mfma4(const u16* __restrict__ qkb,
                                                  const u16* __restrict__ vtg,
                                                  u16* __restrict__ opart,
                                                  float* __restrict__ lpart) {
  const int bx = blockIdx.x;
  const int qt = 15 - (bx >> 6);
  const int r6 = bx & 63;
  const int bh = r6 >> 1, half = r6 & 1;
  const int b = bh >> 4, h = bh & 15;
  const int t = threadIdx.x, lane = t & 63, w = t >> 6;
  const int l15 = lane & 15, quad = lane >> 4;

  __shared__ __align__(16) u16 S[25600];  // 50 KB
  u16* Qs  = S;           // 128x64 swizzled (prologue only; becomes KV buf1)
  u16* KV0 = S + 8192;    // Ks @ +0 (64x64), Vt @ +4096 (64x64)
  u16* KV1 = S;           // aliases Qs
  u16* Pa  = S + 16384;   // 128x72

  const int kt0 = half ? (qt + 1) : 0;
  const int nkt = qt + 1;

  // ---- stage Q ----
  {
    const u16* qb = qkb + ((size_t)(b * SEQ + qt * 128)) * 2048 + h * HDIM;
#pragma unroll
    for (int is = 0; is < 4; ++is) {
      int s = is * 256 + t;
      int row = s >> 3, pos = s & 7;
      int kc = pos ^ (row & 7);
      gload_lds16(qb + (size_t)row * 2048 + kc * 8, &Qs[s * 8]);
    }
  }

#define STAGE_KV(KT, BUF)                                                      \
  {                                                                            \
    const u16* kb_ = qkb + ((size_t)(b * SEQ + (KT) * 64)) * 2048 + NEMBD + h * HDIM; \
    const u16* vb_ = vtg + ((size_t)(bh * 64)) * SEQ + (KT) * 64;              \
    _Pragma("unroll")                                                          \
    for (int is = 0; is < 2; ++is) {                                           \
      int s = is * 256 + t;                                                    \
      int row = s >> 3, pos = s & 7;                                           \
      int kc = pos ^ (row & 7);                                                \
      gload_lds16(kb_ + (size_t)row * 2048 + kc * 8, &(BUF)[s * 8]);           \
      gload_lds16(vb_ + (size_t)row * SEQ + kc * 8, &(BUF)[4096 + s * 8]);     \
    }                                                                          \
  }

  STAGE_KV(kt0, KV0);
  __syncthreads();  // Q + kt0 staged

  short8 qf[2][2];
#pragma unroll
  for (int qs = 0; qs < 2; ++qs) {
    int qrow = w * 32 + qs * 16 + l15;
#pragma unroll
    for (int hf = 0; hf < 2; ++hf)
      qf[qs][hf] = *(const short8*)&Qs[qrow * 64 + (((hf * 4 + quad) ^ (qrow & 7)) * 8)];
  }
  __syncthreads();  // all qf reads done before KV1(=Qs) is overwritten

  float rs[2] = {0.f, 0.f};
  floatx4 o_acc[2][4] = {};

#define COMPUTE_TILE(BUF, KT, MASKED)                                          \
  {                                                                            \
    floatx4 sacc[2][4];                                                        \
    _Pragma("unroll")                                                          \
    for (int nt = 0; nt < 4; ++nt) {                                           \
      int krow = nt * 16 + l15;                                                \
      short8 kf0 = *(const short8*)&(BUF)[krow * 64 + ((quad ^ (krow & 7)) * 8)]; \
      short8 kf1 = *(const short8*)&(BUF)[krow * 64 + (((4 + quad) ^ (krow & 7)) * 8)]; \
      _Pragma("unroll")                                                        \
      for (int qs = 0; qs < 2; ++qs) {                                         \
        floatx4 z = {0.f, 0.f, 0.f, 0.f};                                      \
        z = MFMA16(kf0, qf[qs][0], z);                                         \
        z = MFMA16(kf1, qf[qs][1], z);                                         \
        sacc[qs][nt] = z;                                                      \
      }                                                                        \
    }                                                                          \
    _Pragma("unroll")                                                          \
    for (int qs = 0; qs < 2; ++qs) {                                           \
      const int qg = qt * 128 + w * 32 + qs * 16 + l15;                        \
      const int kb0 = (KT) * 64 + quad * 4;                                    \
      _Pragma("unroll")                                                        \
      for (int nt = 0; nt < 4; ++nt) {                                         \
        ushort4v pk;                                                           \
        _Pragma("unroll")                                                      \
        for (int r = 0; r < 4; ++r) {                                          \
          float p = exp2f(fmaf(sacc[qs][nt][r], SCALE_LOG2E, -8.0f));          \
          if (MASKED && (kb0 + nt * 16 + r) > qg) p = 0.0f;                    \
          rs[qs] += p;                                                         \
          pk[r] = f2bf(p);                                                     \
        }                                                                      \
        *(ushort4v*)&Pa[(w * 32 + qs * 16 + l15) * 72 + nt * 16 + quad * 4] = pk; \
      }                                                                        \
    }                                                                          \
    short8 pf[2][2];                                                           \
    _Pragma("unroll")                                                          \
    for (int qs = 0; qs < 2; ++qs) {                                           \
      const int prow = w * 32 + qs * 16 + l15;                                 \
      pf[qs][0] = *(const short8*)&Pa[prow * 72 + quad * 8];                   \
      pf[qs][1] = *(const short8*)&Pa[prow * 72 + 32 + quad * 8];              \
    }                                                                          \
    _Pragma("unroll")                                                          \
    for (int nt = 0; nt < 4; ++nt) {                                           \
      int drow = nt * 16 + l15;                                                \
      short8 vf0 = *(const short8*)&(BUF)[4096 + drow * 64 + ((quad ^ (drow & 7)) * 8)]; \
      short8 vf1 = *(const short8*)&(BUF)[4096 + drow * 64 + (((4 + quad) ^ (drow & 7)) * 8)]; \
      _Pragma("unroll")                                                        \
      for (int qs = 0; qs < 2; ++qs) {                                         \
        o_acc[qs][nt] = MFMA16(pf[qs][0], vf0, o_acc[qs][nt]);                 \
        o_acc[qs][nt] = MFMA16(pf[qs][1], vf1, o_acc[qs][nt]);                 \
      }                                                                        \
    }                                                                          \
  }

  for (int i = 0; i < nkt; ++i) {
    const int kt = kt0 + i;
    u16* cur = (i & 1) ? KV1 : KV0;
    u16* nxt = (i & 1) ? KV0 : KV1;
    if (i + 1 < nkt) STAGE_KV(kt0 + i + 1, nxt);   // async; drained at iter-end barrier
    if (kt >= 2 * qt) { COMPUTE_TILE(cur, kt, 1); }
    else              { COMPUTE_TILE(cur, kt, 0); }
    __syncthreads();  // single barrier: next staging visible + cur reads done
  }
#undef COMPUTE_TILE
#undef STAGE_KV

  // ---- epilogue: reduce l over quads, store partials ----
#pragma unroll
  for (int qs = 0; qs < 2; ++qs) {
    rs[qs] += __shfl_xor(rs[qs], 16, 64);
    rs[qs] += __shfl_xor(rs[qs], 32, 64);
    if (quad == 0)
      lpart[((size_t)half * 32 + bh) * SEQ + qt * 128 + w * 32 + qs * 16 + l15] = rs[qs];
  }
  u16* ob = opart + (size_t)half * BT * NEMBD;
#pragma unroll
  for (int qs = 0; qs < 2; ++qs)
#pragma unroll
    for (int nt = 0; nt < 4; ++nt)
#pragma unroll
      for (int r = 0; r < 4; ++r) {
        size_t tok = (size_t)(b * SEQ + qt * 128 + w * 32 + qs * 16 + quad * 4 + r);
        ob[tok * NEMBD + h * HDIM + nt * 16 + l15] = f2bf(o_acc[qs][nt][r]);
      }
}

// ---------------------------------------------------------------------------
// Combine split-K partials: yb = (O0 + O1) / (l0 + l1), bf16.
// ---------------------------------------------------------------------------
__global__ __launch_bounds__(256) void combine(const u16* __restrict__ opart,
                                               const float* __restrict__ lpart,
                                               u16* __restrict__ yb) {
  int idx = (blockIdx.x * 256 + threadIdx.x) * 4;
  int tok = idx >> 10, c = idx & 1023;
  int b = tok >> 11, q = tok & (SEQ - 1), h = c >> 6;
  float l = lpart[(size_t)(b * 16 + h) * SEQ + q] +
            lpart[(size_t)(32 + b * 16 + h) * SEQ + q];
  float inv = 1.0f / l;
  ushort4v o0 = *(const ushort4v*)&opart[idx];
  ushort4v o1 = *(const ushort4v*)&opart[(size_t)BT * NEMBD + idx];
  ushort4v yo;
#pragma unroll
  for (int j = 0; j < 4; ++j) {
    float f0 = bf2f(o0[j]);
    float f1 = bf2f(o1[j]);
    yo[j] = f2bf((f0 + f1) * inv);
  }
  *(ushort4v*)&yb[idx] = yo;
}

// ---------------------------------------------------------------------------
// GEMM2: out(fp32) = yb @ w_proj^T. 128x64 tile, BK=64 swizzled, operand-
// swapped -> float4 stores. Async-LDS ping-pong (2x24 KB = 48 KB, 3 blk/CU),
// ONE barrier per K-iter (attn_mfma4's proven pattern). 512 blocks.
// ---------------------------------------------------------------------------
__global__ __launch_bounds__(256) void gemm_out(const u16* __restrict__ A,
                                                const u16* __restrict__ B,
                                                float* __restrict__ C) {
  __shared__ __align__(16) u16 S[2][12288];   // [buf][ As 8192 | Bs 4096 ]
  const int t = threadIdx.x;
  const int lane = t & 63, w = t >> 6;
  const int l15 = lane & 15, quad = lane >> 4;
  const int wm = w >> 1, wn = w & 1;
  const int m0 = blockIdx.y * 128, n0 = blockIdx.x * 64;

  const int srow8 = t >> 3;
  const int kc = (t & 7) ^ (srow8 & 7);

#define OUT_STAGE(K0, BUF)                                                     \
  { u16* as_ = &S[BUF][0]; u16* bs_ = &S[BUF][8192];                           \
    _Pragma("unroll")                                                          \
    for (int is = 0; is < 4; ++is)                                             \
      gload_lds16(A + (size_t)(m0 + is * 32 + srow8) * NEMBD + (K0) + kc * 8,  \
                  &as_[(is * 256 + t) * 8]);                                   \
    _Pragma("unroll")                                                          \
    for (int is = 0; is < 2; ++is)                                             \
      gload_lds16(B + (size_t)(n0 + is * 32 + srow8) * NEMBD + (K0) + kc * 8,  \
                  &bs_[(is * 256 + t) * 8]); }

  floatx4 acc[4][2] = {};

  OUT_STAGE(0, 0);
  __syncthreads();

  int ib = 0;
  for (int k0 = 0; k0 < NEMBD; k0 += 64, ib ^= 1) {
    if (k0 + 64 < NEMBD) OUT_STAGE(k0 + 64, ib ^ 1);   // async into alt buffer
    const u16* as_ = &S[ib][0];
    const u16* bs_ = &S[ib][8192];
#pragma unroll
    for (int kh = 0; kh < 2; ++kh) {
      short8 af[4], bfr[2];
#pragma unroll
      for (int mt = 0; mt < 4; ++mt) {
        int row = wm * 64 + mt * 16 + l15;
        af[mt] = *(const short8*)&as_[row * 64 + (((kh * 4 + quad) ^ (row & 7)) * 8)];
      }
#pragma unroll
      for (int nt = 0; nt < 2; ++nt) {
        int row = wn * 32 + nt * 16 + l15;
        bfr[nt] = *(const short8*)&bs_[row * 64 + (((kh * 4 + quad) ^ (row & 7)) * 8)];
      }
#pragma unroll
      for (int mt = 0; mt < 4; ++mt)
#pragma unroll
        for (int nt = 0; nt < 2; ++nt)
          acc[mt][nt] = MFMA16(bfr[nt], af[mt], acc[mt][nt]);   // D[n][m]
    }
    __syncthreads();   // staging of k0+64 visible + reads of ib done
  }
#undef OUT_STAGE

  // swapped: rows = n (quad*4+r), cols = token (l15) -> float4 stores
#pragma unroll
  for (int mt = 0; mt < 4; ++mt) {
    size_t token = (size_t)(m0 + wm * 64 + mt * 16 + l15);
#pragma unroll
    for (int nt = 0; nt < 2; ++nt) {
      int nc = n0 + wn * 32 + nt * 16 + quad * 4;
      float4 v = make_float4(acc[mt][nt][0], acc[mt][nt][1],
                             acc[mt][nt][2], acc[mt][nt][3]);
      *(float4*)&C[token * NEMBD + nc] = v;
    }
  }
}

// ---------------------------------------------------------------------------
extern "C" void kernel_launch(void* const* d_in, const int* in_sizes, int n_in,
                              void* d_out, int out_size, void* d_ws, size_t ws_size,
                              hipStream_t stream) {
  const float* x      = (const float*)d_in[0];
  const float* w_attn = (const float*)d_in[1];
  const float* w_proj = (const float*)d_in[2];
  float* out = (float*)d_out;

  // Workspace (u16 units). opart ALIASES xb+wab (dead after gemm_qkv).
  u16* base  = (u16*)d_ws;
  u16* opart = base;                       // 2*4096*1024 u16 = 16 MB
  u16* xb    = base;                       // alias
  u16* wab   = base + 4194304;             // alias
  u16* wpb   = base + 8388608;             // 2 MB
  u16* qkb   = base + 9437184;             // 16 MB
  u16* vtg   = base + 17825792;            // 8 MB
  u16* yb    = base + 22020096;            // 8 MB
  float* lpart = (float*)(base + 26214400);  // 0.5 MB

  cvt_all<<<(N_X + N_WA + N_WP) / 2048, 256, 0, stream>>>(x, w_attn, w_proj, xb, wab, wpb);

  gemm_qkv<<<dim3(QKV_LD / 128, BT / 128), 256, 0, stream>>>(xb, wab, qkb, vtg);

  attn_mfma4<<<dim3((SEQ / 128) * BSZ * NHEAD * 2), 256, 0, stream>>>(qkb, vtg, opart, lpart);

  combine<<<(BT * NEMBD) / 1024, 256, 0, stream>>>(opart, lpart, yb);

  gemm_out<<<dim3(NEMBD / 64, BT / 128), 256, 0, stream>>>(yb, wpb, out);
}